// Round 4
// baseline (399.779 us; speedup 1.0000x reference)
//
#include <hip/hip_runtime.h>
#include <math.h>
#include <cstdint>
#include <cstddef>

// Problem constants (fixed by the reference)
#define BB 32
#define TT 2048
#define HH 1024
#define UU 1024
#define NBK 32         // chunk-blocks per batch
#define BT 64          // timesteps per block (NBK*BT == TT)
#define WT 16          // timesteps per wave (4 waves * WT == BT)
#define NEG_BIG (-1e9f)

// ---------------------------------------------------------------------------
// Kernel 0: v[b,h] = sum_u Wa[h,u] * dec[b,u]
// 512 blocks x 2 h-rows (was 256 x 4): k_v is latency-bound on its shfl
// chains at 1 block/CU, so halving per-block serial work and doubling the
// block count cuts its critical path ~2x. Rows staged in LDS (8 KB).
// ---------------------------------------------------------------------------
__global__ __launch_bounds__(256) void k_v(const float* __restrict__ Wa,
                                           const float* __restrict__ dec,
                                           float* __restrict__ v) {
    __shared__ float lds[2 * UU];          // 2 rows x 1024 floats = 8 KB
    const int tid = threadIdx.x;
    const int h0  = blockIdx.x * 2;

    const float4* Wa4  = reinterpret_cast<const float4*>(Wa + (size_t)h0 * UU);
    float4*       lds4 = reinterpret_cast<float4*>(lds);
    #pragma unroll
    for (int i = 0; i < 2; ++i)
        lds4[i * 256 + tid] = Wa4[i * 256 + tid];   // coalesced row loads
    __syncthreads();

    const int wid = tid >> 6, lane = tid & 63;
    for (int j = 0; j < 8; ++j) {
        const int b = wid * 8 + j;
        const float4* d4 = reinterpret_cast<const float4*>(dec + (size_t)b * UU);
        float4 dreg[4];
        #pragma unroll
        for (int k = 0; k < 4; ++k) dreg[k] = d4[k * 64 + lane];

        float p[2];
        #pragma unroll
        for (int r = 0; r < 2; ++r) {
            float acc = 0.f;
            #pragma unroll
            for (int k = 0; k < 4; ++k) {
                const float4 a = lds4[r * 256 + k * 64 + lane];
                acc += a.x * dreg[k].x + a.y * dreg[k].y +
                       a.z * dreg[k].z + a.w * dreg[k].w;
            }
            p[r] = acc;
        }
        #pragma unroll
        for (int r = 0; r < 2; ++r) {
            #pragma unroll
            for (int off = 32; off > 0; off >>= 1)
                p[r] += __shfl_xor(p[r], off, 64);   // two independent chains
        }
        if (lane == 0) {
            v[(size_t)b * HH + h0]     = p[0];
            v[(size_t)b * HH + h0 + 1] = p[1];
        }
    }
}

// ---------------------------------------------------------------------------
// Kernel 1: flash pass + fused per-batch combine.
// Each block owns 64 consecutive t; 4 waves x 16 t, register-resident online
// softmax. Masked t never touch memory OR the update loop: ballot->bits,
// iterate set bits only. exp(-1e9 - m) == 0 exactly in fp32 whenever the
// wave saw any unmasked score, so masked t's only effect is the all-masked
// case (m=-1e9, l=count) — handled by one popcount. After the block's LDS
// combine writes its partial, the LAST block per batch (device-scope atomic
// counter) performs the final 32-partial combine — no k_reduce launch, and
// the combine overlaps the flash tail.
// ---------------------------------------------------------------------------
__global__ __launch_bounds__(256, 4) void k_flash(const float* __restrict__ enc,
                                                  const int* __restrict__ mask,
                                                  const float* __restrict__ v,
                                                  float* __restrict__ pm,
                                                  float* __restrict__ pl,
                                                  float* __restrict__ pctx,
                                                  int* __restrict__ cnt,
                                                  float* __restrict__ out) {
    const int tid  = threadIdx.x;
    const int wid  = tid >> 6, lane = tid & 63;
    const int bk   = blockIdx.x;             // 0..B*NBK-1
    const int b    = bk >> 5;                // bk / NBK
    const int c    = bk & (NBK - 1);
    const int t0   = c * BT + wid * WT;

    // v[b] fragment: lane's h-slice is {(k*64+lane)*4 .. +3} for k=0..3
    const float4* v4 = reinterpret_cast<const float4*>(v + (size_t)b * HH);
    float4 vr[4];
    #pragma unroll
    for (int k = 0; k < 4; ++k) vr[k] = v4[k * 64 + lane];

    // Wave-uniform unmasked-t bitmask via one broadcast load + ballot.
    const int* mrow = mask + (size_t)b * TT + t0;
    const int  myb  = (lane < WT) ? mrow[lane] : 0;
    unsigned   bits = (unsigned)(__ballot(myb != 0) & 0xFFFFu);
    const int  nmask = WT - __popc(bits);

    float m = -INFINITY, l = 0.f;
    float4 ctx[4];
    #pragma unroll
    for (int k = 0; k < 4; ++k) ctx[k] = make_float4(0.f, 0.f, 0.f, 0.f);

    const float4* erow = reinterpret_cast<const float4*>(
                             enc + ((size_t)b * TT + t0) * HH);

    while (bits) {                                     // unmasked t only
        const int t = __ffs(bits) - 1;
        bits &= bits - 1;

        float4 e[4];
        #pragma unroll
        for (int k = 0; k < 4; ++k)
            e[k] = erow[(size_t)t * 256 + k * 64 + lane];  // 4 KB/row coalesced

        float p = 0.f;
        #pragma unroll
        for (int k = 0; k < 4; ++k)
            p += e[k].x * vr[k].x + e[k].y * vr[k].y +
                 e[k].z * vr[k].z + e[k].w * vr[k].w;
        #pragma unroll
        for (int off = 32; off > 0; off >>= 1)
            p += __shfl_xor(p, off, 64);

        const float mnew  = fmaxf(m, p);
        const float alpha = __expf(m - mnew);          // m=-inf first iter -> 0
        const float pe    = __expf(p - mnew);
        l = l * alpha + pe;
        #pragma unroll
        for (int k = 0; k < 4; ++k) {
            ctx[k].x = ctx[k].x * alpha + pe * e[k].x;
            ctx[k].y = ctx[k].y * alpha + pe * e[k].y;
            ctx[k].z = ctx[k].z * alpha + pe * e[k].z;
            ctx[k].w = ctx[k].w * alpha + pe * e[k].w;
        }
        m = mnew;
    }
    if (m == -INFINITY) {          // all 16 t masked: scores all -1e9 exactly
        m = NEG_BIG;
        l = (float)nmask;
    }
    // (mixed case: masked t contribute exp(-1e9 - m) == 0 exactly in fp32,
    //  since m >= a real score >> -1e9+104; nothing to add.)

    // ---- block-level combine of the 4 wave states (LDS, exact) ----
    __shared__ float4 sctx[4 * 256];                   // 16 KB
    __shared__ float  sm[4], sl[4];
    __shared__ int    sLast;
    #pragma unroll
    for (int k = 0; k < 4; ++k)
        sctx[wid * 256 + k * 64 + lane] = ctx[k];
    if (lane == 0) { sm[wid] = m; sl[wid] = l; }
    __syncthreads();

    const float M  = fmaxf(fmaxf(sm[0], sm[1]), fmaxf(sm[2], sm[3]));  // >= -1e9
    const float a0 = __expf(sm[0] - M), a1 = __expf(sm[1] - M);
    const float a2 = __expf(sm[2] - M), a3 = __expf(sm[3] - M);
    const float L  = sl[0] * a0 + sl[1] * a1 + sl[2] * a2 + sl[3] * a3;

    const float4 x0 = sctx[tid], x1 = sctx[256 + tid];
    const float4 x2 = sctx[512 + tid], x3 = sctx[768 + tid];
    float4 r;
    r.x = a0 * x0.x + a1 * x1.x + a2 * x2.x + a3 * x3.x;
    r.y = a0 * x0.y + a1 * x1.y + a2 * x2.y + a3 * x3.y;
    r.z = a0 * x0.z + a1 * x1.z + a2 * x2.z + a3 * x3.z;
    r.w = a0 * x0.w + a1 * x1.w + a2 * x2.w + a3 * x3.w;

    reinterpret_cast<float4*>(pctx + (size_t)bk * HH)[tid] = r;
    if (tid == 0) { pm[bk] = M; pl[bk] = L; }

    // ---- last block per batch performs the final combine ----
    __syncthreads();               // all waves drain their stores (vmcnt 0)
    if (tid == 0) {
        __threadfence();           // release: partials device-visible
        sLast = (atomicAdd(&cnt[b], 1) == NBK - 1);
    }
    __syncthreads();
    if (!sLast) return;
    __threadfence();               // acquire: don't read stale partials

    __shared__ float fm[NBK], fl[NBK];
    if (tid < NBK) {
        fm[tid] = pm[b * NBK + tid];
        fl[tid] = pl[b * NBK + tid];
    }
    __syncthreads();

    float FM = -INFINITY;
    #pragma unroll
    for (int k = 0; k < NBK; ++k) FM = fmaxf(FM, fm[k]);   // LDS broadcast

    const float4* p4 = reinterpret_cast<const float4*>(pctx) +
                       (size_t)b * NBK * 256 + tid;
    float FL = 0.f;
    float4 acc = make_float4(0.f, 0.f, 0.f, 0.f);
    #pragma unroll 4
    for (int k = 0; k < NBK; ++k) {
        const float e = __expf(fm[k] - FM);
        FL += fl[k] * e;
        const float4 x = p4[k * 256];
        acc.x += e * x.x; acc.y += e * x.y;
        acc.z += e * x.z; acc.w += e * x.w;
    }
    const float inv = 1.f / FL;    // FL >= 1 (max chunk contributes pe=1)
    acc.x *= inv; acc.y *= inv; acc.z *= inv; acc.w *= inv;
    reinterpret_cast<float4*>(out)[(size_t)b * 256 + tid] = acc;
}

// ---------------------------------------------------------------------------
extern "C" void kernel_launch(void* const* d_in, const int* in_sizes, int n_in,
                              void* d_out, int out_size, void* d_ws, size_t ws_size,
                              hipStream_t stream) {
    const float* enc  = (const float*)d_in[0];   // (B,T,H) fp32
    const float* dec  = (const float*)d_in[1];   // (B,H)   fp32
    const int*   mask = (const int*)  d_in[2];   // (B,T)   bool->int32
    const float* Wa   = (const float*)d_in[3];   // (H,U)   fp32
    float*       out  = (float*)d_out;           // (B,H)   fp32

    // Workspace layout (floats): v | pm | pl | cnt | pctx  (~4.3 MB total)
    float* ws   = (float*)d_ws;
    float* v    = ws;                            // B*H      = 32768
    float* pm   = v  + (size_t)BB * HH;          // B*NBK    = 1024
    float* pl   = pm + (size_t)BB * NBK;         // B*NBK    = 1024
    int*   cnt  = (int*)(pl + (size_t)BB * NBK); // B ints (1024-float slot)
    float* pctx = pl + (size_t)BB * NBK + 1024;  // B*NBK*H  = 1048576 (16B-aligned)

    // ws is re-poisoned to 0xAA before every replay: zero the counters.
    hipMemsetAsync(cnt, 0, BB * sizeof(int), stream);
    k_v<<<HH / 2, 256, 0, stream>>>(Wa, dec, v);
    k_flash<<<BB * NBK, 256, 0, stream>>>(enc, mask, v, pm, pl, pctx, cnt, out);
}

// Round 5
// 349.333 us; speedup vs baseline: 1.1444x; 1.1444x over previous
//
#include <hip/hip_runtime.h>
#include <math.h>
#include <cstdint>
#include <cstddef>

// Problem constants (fixed by the reference)
#define BB 32
#define TT 2048
#define HH 1024
#define UU 1024
#define NBK 32         // chunk-blocks per batch
#define BT 64          // timesteps per block (NBK*BT == TT)
#define WT 16          // timesteps per wave (4 waves * WT == BT)
#define NEG_BIG (-1e9f)

// ---------------------------------------------------------------------------
// Kernel 0: v[b,h] = sum_u Wa[h,u] * dec[b,u]
// 512 blocks x 2 h-rows: k_v is latency-bound on its shfl chains at
// ~1-2 blocks/CU, so small per-block serial work + many blocks wins.
// ---------------------------------------------------------------------------
__global__ __launch_bounds__(256) void k_v(const float* __restrict__ Wa,
                                           const float* __restrict__ dec,
                                           float* __restrict__ v) {
    __shared__ float lds[2 * UU];          // 2 rows x 1024 floats = 8 KB
    const int tid = threadIdx.x;
    const int h0  = blockIdx.x * 2;

    const float4* Wa4  = reinterpret_cast<const float4*>(Wa + (size_t)h0 * UU);
    float4*       lds4 = reinterpret_cast<float4*>(lds);
    #pragma unroll
    for (int i = 0; i < 2; ++i)
        lds4[i * 256 + tid] = Wa4[i * 256 + tid];   // coalesced row loads
    __syncthreads();

    const int wid = tid >> 6, lane = tid & 63;
    for (int j = 0; j < 8; ++j) {
        const int b = wid * 8 + j;
        const float4* d4 = reinterpret_cast<const float4*>(dec + (size_t)b * UU);
        float4 dreg[4];
        #pragma unroll
        for (int k = 0; k < 4; ++k) dreg[k] = d4[k * 64 + lane];

        float p[2];
        #pragma unroll
        for (int r = 0; r < 2; ++r) {
            float acc = 0.f;
            #pragma unroll
            for (int k = 0; k < 4; ++k) {
                const float4 a = lds4[r * 256 + k * 64 + lane];
                acc += a.x * dreg[k].x + a.y * dreg[k].y +
                       a.z * dreg[k].z + a.w * dreg[k].w;
            }
            p[r] = acc;
        }
        #pragma unroll
        for (int r = 0; r < 2; ++r) {
            #pragma unroll
            for (int off = 32; off > 0; off >>= 1)
                p[r] += __shfl_xor(p[r], off, 64);   // two independent chains
        }
        if (lane == 0) {
            v[(size_t)b * HH + h0]     = p[0];
            v[(size_t)b * HH + h0 + 1] = p[1];
        }
    }
}

// ---------------------------------------------------------------------------
// Kernel 1: flash-style single pass over enc_hs (R3 structure — NO fences,
// NO atomics; the fused last-block combine regressed +52us in R4 because
// 1024 device-scope __threadfence L2-writebacks serialized).
// Each block owns 64 consecutive t; 4 waves x 16 t with register-resident
// online softmax. Masked t never touch memory OR the update loop:
// ballot->bits, iterate set bits only. exp(-1e9-m) == 0 exactly in fp32
// whenever the wave saw any real score; the all-masked case is one popcount
// (m=-1e9, l=count), keeping the all-masked batch edge case exact.
// Block merges its 4 wave states in LDS and writes ONE partial.
// ---------------------------------------------------------------------------
__global__ __launch_bounds__(256, 4) void k_flash(const float* __restrict__ enc,
                                                  const int* __restrict__ mask,
                                                  const float* __restrict__ v,
                                                  float* __restrict__ pm,
                                                  float* __restrict__ pl,
                                                  float* __restrict__ pctx) {
    const int tid  = threadIdx.x;
    const int wid  = tid >> 6, lane = tid & 63;
    const int bk   = blockIdx.x;             // 0..B*NBK-1
    const int b    = bk >> 5;                // bk / NBK
    const int c    = bk & (NBK - 1);
    const int t0   = c * BT + wid * WT;

    // v[b] fragment: lane's h-slice is {(k*64+lane)*4 .. +3} for k=0..3
    const float4* v4 = reinterpret_cast<const float4*>(v + (size_t)b * HH);
    float4 vr[4];
    #pragma unroll
    for (int k = 0; k < 4; ++k) vr[k] = v4[k * 64 + lane];

    // Wave-uniform unmasked-t bitmask via one broadcast load + ballot.
    const int* mrow = mask + (size_t)b * TT + t0;
    const int  myb  = (lane < WT) ? mrow[lane] : 0;
    unsigned   bits = (unsigned)(__ballot(myb != 0) & 0xFFFFu);
    const int  nmask = WT - __popc(bits);

    float m = -INFINITY, l = 0.f;
    float4 ctx[4];
    #pragma unroll
    for (int k = 0; k < 4; ++k) ctx[k] = make_float4(0.f, 0.f, 0.f, 0.f);

    const float4* erow = reinterpret_cast<const float4*>(
                             enc + ((size_t)b * TT + t0) * HH);

    while (bits) {                                     // unmasked t only
        const int t = __ffs(bits) - 1;
        bits &= bits - 1;

        float4 e[4];
        #pragma unroll
        for (int k = 0; k < 4; ++k)
            e[k] = erow[(size_t)t * 256 + k * 64 + lane];  // 4 KB/row coalesced

        float p = 0.f;
        #pragma unroll
        for (int k = 0; k < 4; ++k)
            p += e[k].x * vr[k].x + e[k].y * vr[k].y +
                 e[k].z * vr[k].z + e[k].w * vr[k].w;
        #pragma unroll
        for (int off = 32; off > 0; off >>= 1)
            p += __shfl_xor(p, off, 64);

        const float mnew  = fmaxf(m, p);
        const float alpha = __expf(m - mnew);          // m=-inf first iter -> 0
        const float pe    = __expf(p - mnew);
        l = l * alpha + pe;
        #pragma unroll
        for (int k = 0; k < 4; ++k) {
            ctx[k].x = ctx[k].x * alpha + pe * e[k].x;
            ctx[k].y = ctx[k].y * alpha + pe * e[k].y;
            ctx[k].z = ctx[k].z * alpha + pe * e[k].z;
            ctx[k].w = ctx[k].w * alpha + pe * e[k].w;
        }
        m = mnew;
    }
    if (m == -INFINITY) {          // all 16 t masked: scores all -1e9 exactly
        m = NEG_BIG;
        l = (float)nmask;
    }
    // (mixed case: masked t contribute exp(-1e9 - m) == 0 exactly in fp32.)

    // ---- block-level combine of the 4 wave states (LDS, exact) ----
    __shared__ float4 sctx[4 * 256];                   // 16 KB
    __shared__ float  sm[4], sl[4];
    #pragma unroll
    for (int k = 0; k < 4; ++k)
        sctx[wid * 256 + k * 64 + lane] = ctx[k];
    if (lane == 0) { sm[wid] = m; sl[wid] = l; }
    __syncthreads();

    const float M  = fmaxf(fmaxf(sm[0], sm[1]), fmaxf(sm[2], sm[3]));  // >= -1e9
    const float a0 = __expf(sm[0] - M), a1 = __expf(sm[1] - M);
    const float a2 = __expf(sm[2] - M), a3 = __expf(sm[3] - M);
    const float L  = sl[0] * a0 + sl[1] * a1 + sl[2] * a2 + sl[3] * a3;

    const float4 x0 = sctx[tid], x1 = sctx[256 + tid];
    const float4 x2 = sctx[512 + tid], x3 = sctx[768 + tid];
    float4 r;
    r.x = a0 * x0.x + a1 * x1.x + a2 * x2.x + a3 * x3.x;
    r.y = a0 * x0.y + a1 * x1.y + a2 * x2.y + a3 * x3.y;
    r.z = a0 * x0.z + a1 * x1.z + a2 * x2.z + a3 * x3.z;
    r.w = a0 * x0.w + a1 * x1.w + a2 * x2.w + a3 * x3.w;

    reinterpret_cast<float4*>(pctx + (size_t)bk * HH)[tid] = r;
    if (tid == 0) { pm[bk] = M; pl[bk] = L; }
}

// ---------------------------------------------------------------------------
// Kernel 2: combine the NBK block partials per batch.
// grid (B, H/256); thread owns one h. 4 MB of pctx to read.
// ---------------------------------------------------------------------------
__global__ __launch_bounds__(256) void k_reduce(const float* __restrict__ pm,
                                                const float* __restrict__ pl,
                                                const float* __restrict__ pctx,
                                                float* __restrict__ out) {
    const int b = blockIdx.x;
    const int h = blockIdx.y * 256 + threadIdx.x;
    __shared__ float sm[NBK], sl[NBK];

    if (threadIdx.x < NBK) {
        sm[threadIdx.x] = pm[b * NBK + threadIdx.x];
        sl[threadIdx.x] = pl[b * NBK + threadIdx.x];
    }
    __syncthreads();

    float M = -INFINITY;
    #pragma unroll
    for (int c = 0; c < NBK; ++c) M = fmaxf(M, sm[c]);   // LDS broadcast reads

    float L = 0.f, acc = 0.f;
    #pragma unroll 4
    for (int c = 0; c < NBK; ++c) {
        const float e = __expf(sm[c] - M);
        L   += sl[c] * e;
        acc += e * pctx[((size_t)b * NBK + c) * HH + h];
    }

    out[(size_t)b * HH + h] = acc / L;   // L >= 1 (max chunk contributes pe=1)
}

// ---------------------------------------------------------------------------
extern "C" void kernel_launch(void* const* d_in, const int* in_sizes, int n_in,
                              void* d_out, int out_size, void* d_ws, size_t ws_size,
                              hipStream_t stream) {
    const float* enc  = (const float*)d_in[0];   // (B,T,H) fp32
    const float* dec  = (const float*)d_in[1];   // (B,H)   fp32
    const int*   mask = (const int*)  d_in[2];   // (B,T)   bool->int32
    const float* Wa   = (const float*)d_in[3];   // (H,U)   fp32
    float*       out  = (float*)d_out;           // (B,H)   fp32

    // Workspace layout (floats): v | pm | pl | pctx  (~4.3 MB total)
    float* ws   = (float*)d_ws;
    float* v    = ws;                            // B*H      = 32768
    float* pm   = v  + (size_t)BB * HH;          // B*NBK    = 1024
    float* pl   = pm + (size_t)BB * NBK;         // B*NBK    = 1024
    float* pctx = pl + (size_t)BB * NBK;         // B*NBK*H  = 1048576

    k_v<<<HH / 2, 256, 0, stream>>>(Wa, dec, v);
    k_flash<<<BB * NBK, 256, 0, stream>>>(enc, mask, v, pm, pl, pctx);
    dim3 g2(BB, HH / 256);
    k_reduce<<<g2, 256, 0, stream>>>(pm, pl, pctx, out);
}